// Round 1
// baseline (303.865 us; speedup 1.0000x reference)
//
#include <hip/hip_runtime.h>

// out[b,m,c] = sum_{k<3} vals[m,k] * x[b, cols[m,k], c]
// B=8, N=50000, C=128, M=25000, K=3, fp32.
//
// Single-pass direct gather with 4 m's per thread (m, m+M/4, m+2M/4, m+3M/4):
//  - 12 independent gather loads in flight per thread (2x the previous 6)
//    to cover HBM-miss latency (~900 cy) during cohort transitions.
//  - all cols/vals index loads hoisted before any gather.
//  - non-temporal stores for out: keep the 102 MB write stream out of L2/L3
//    so x (204.8 MB, fits the 256 MB L3; ~19.9 MB touched per b-slab) keeps
//    its ~1.9x reuse resident.
//  - b-major thread order: blocks sweep one b-slab at a time -> L3 locality.
// Uses clang ext_vector float4 (v4f) because __builtin_nontemporal_store
// rejects HIP_vector_type.

#define B_ 8
#define N_ 50000
#define C_ 128
#define M_ 25000
#define MQ 6250   // M/4

typedef float v4f __attribute__((ext_vector_type(4)));

__global__ __launch_bounds__(256) void mesh_gather_kernel(
    const float* __restrict__ x,      // [B, N, C]
    const int* __restrict__ cols,     // [M, 3]
    const float* __restrict__ vals,   // [M, 3]
    float* __restrict__ out)          // [B, M, C]
{
    int t = blockIdx.x * blockDim.x + threadIdx.x;   // < B*MQ*32 = 1.6M exactly

    int c4 = t & 31;                 // float4 index within the 128-float row
    int mq = (t >> 5) % MQ;
    int b  = t / (MQ * 32);

    // 4 independent m's per thread
    int m0 = mq;
    int m1 = mq + MQ;
    int m2 = mq + 2 * MQ;
    int m3 = mq + 3 * MQ;

    // hoist ALL index/weight loads first (small, L2-hot, 600 KB total)
    int idx[12];
    float w[12];
    #pragma unroll
    for (int k = 0; k < 3; ++k) {
        idx[0 + k] = cols[m0 * 3 + k];
        idx[3 + k] = cols[m1 * 3 + k];
        idx[6 + k] = cols[m2 * 3 + k];
        idx[9 + k] = cols[m3 * 3 + k];
        w[0 + k] = vals[m0 * 3 + k];
        w[3 + k] = vals[m1 * 3 + k];
        w[6 + k] = vals[m2 * 3 + k];
        w[9 + k] = vals[m3 * 3 + k];
    }

    const v4f* xb = (const v4f*)(x + (long long)b * N_ * C_);

    // 12 independent gather loads in flight; row offsets fit in 32-bit
    // (idx*32 + c4 < 1.6M float4s per slab)
    v4f g[12];
    #pragma unroll
    for (int j = 0; j < 12; ++j)
        g[j] = xb[idx[j] * 32 + c4];

    v4f r0 = w[0] * g[0] + w[1]  * g[1]  + w[2]  * g[2];
    v4f r1 = w[3] * g[3] + w[4]  * g[4]  + w[5]  * g[5];
    v4f r2 = w[6] * g[6] + w[7]  * g[7]  + w[8]  * g[8];
    v4f r3 = w[9] * g[9] + w[10] * g[10] + w[11] * g[11];

    v4f* out4 = (v4f*)out + (long long)b * M_ * 32 + c4;
    __builtin_nontemporal_store(r0, &out4[(long long)m0 * 32]);
    __builtin_nontemporal_store(r1, &out4[(long long)m1 * 32]);
    __builtin_nontemporal_store(r2, &out4[(long long)m2 * 32]);
    __builtin_nontemporal_store(r3, &out4[(long long)m3 * 32]);
}

extern "C" void kernel_launch(void* const* d_in, const int* in_sizes, int n_in,
                              void* d_out, int out_size, void* d_ws, size_t ws_size,
                              hipStream_t stream) {
    const float* x    = (const float*)d_in[0];
    const int*   cols = (const int*)d_in[1];
    const float* vals = (const float*)d_in[2];
    float* out = (float*)d_out;

    const int total = B_ * MQ * (C_ / 4);   // 1,600,000 == 6250 * 256 exactly
    const int block = 256;
    const int grid = total / block;          // 6250
    mesh_gather_kernel<<<grid, block, 0, stream>>>(x, cols, vals, out);
}